// Round 1
// baseline (183.929 us; speedup 1.0000x reference)
//
#include <hip/hip_runtime.h>

#define BATCH 4096
#define SEQ   128
#define DIN   64
#define DOUT  128
#define HID   32

// One wave (64 lanes) per batch element.
__global__ __launch_bounds__(64) void fused_mlp_topk_kernel(
    const float* __restrict__ x,      // (B, S, DIN)
    const float* __restrict__ Wn,     // (DIN, DOUT)
    const float* __restrict__ bn,     // (DOUT)
    const float* __restrict__ W1,     // (DOUT, HID)
    const float* __restrict__ b1,     // (HID)
    const float* __restrict__ W2,     // (HID, 4)
    const float* __restrict__ b2,     // (4)
    const int*   __restrict__ mask,   // (B, S) as int32 0/1
    float*       __restrict__ out)    // (B, 2, 4)
{
    const int b    = blockIdx.x;
    const int lane = threadIdx.x;   // 0..63

    // ---- find first two valid (mask=True) positions, stable order ----
    // lane covers s=lane and s=lane+64
    const int m0 = mask[b * SEQ + lane];
    const int m1 = mask[b * SEQ + 64 + lane];
    const unsigned long long bal0 = __ballot(m0 != 0);
    const unsigned long long bal1 = __ballot(m1 != 0);

    int i0 = 0, i1 = 0, cnt = 0;
    if (bal0) {
        i0 = __builtin_ctzll(bal0);
        unsigned long long rem = bal0 & (bal0 - 1ull);
        if (rem)       { i1 = __builtin_ctzll(rem);       cnt = 2; }
        else if (bal1) { i1 = 64 + __builtin_ctzll(bal1); cnt = 2; }
        else           { i1 = i0;                         cnt = 1; }
    } else if (bal1) {
        i0 = 64 + __builtin_ctzll(bal1);
        unsigned long long rem = bal1 & (bal1 - 1ull);
        if (rem) { i1 = 64 + __builtin_ctzll(rem); cnt = 2; }
        else     { i1 = i0;                        cnt = 1; }
    }
    // cnt==1: i1=i0 so preds1==preds0, matching the nv==1 "where" branch.

    // ---- load the two selected x rows (lane holds x[row][lane]) ----
    const size_t xbase = (size_t)b * SEQ * DIN;
    const float x0 = x[xbase + (size_t)i0 * DIN + lane];
    const float x1 = x[xbase + (size_t)i1 * DIN + lane];

    // ---- layer 0: feats = x_row @ Wn + bn  (lane -> cols lane, lane+64) ----
    float f00 = bn[lane], f01 = bn[lane + 64];   // row 0
    float f10 = f00,      f11 = f01;             // row 1 (same bias start)
    #pragma unroll 8
    for (int d = 0; d < DIN; ++d) {
        const float w0 = Wn[d * DOUT + lane];
        const float w1 = Wn[d * DOUT + 64 + lane];
        const float xa = __shfl(x0, d);
        const float xb = __shfl(x1, d);
        f00 = fmaf(xa, w0, f00);
        f01 = fmaf(xa, w1, f01);
        f10 = fmaf(xb, w0, f10);
        f11 = fmaf(xb, w1, f11);
    }

    __shared__ float feats[2][DOUT];
    feats[0][lane]      = f00;
    feats[0][lane + 64] = f01;
    feats[1][lane]      = f10;
    feats[1][lane + 64] = f11;
    __syncthreads();

    // ---- layer 1: h = relu(feats @ W1 + b1); lanes 0-31 row0, 32-63 row1 ----
    const int r = lane >> 5;
    const int k = lane & 31;
    float h = b1[k];
    #pragma unroll 8
    for (int j = 0; j < DOUT; ++j) {
        h = fmaf(feats[r][j], W1[j * HID + k], h);
    }
    h = fmaxf(h, 0.0f);

    __shared__ float hsm[2][HID];
    hsm[r][k] = h;
    __syncthreads();

    // ---- layer 2 + selection: lanes 0..7 -> out[b][rr][o] ----
    if (lane < 8) {
        const int rr = lane >> 2;
        const int o  = lane & 3;
        float p = b2[o];
        #pragma unroll
        for (int kk = 0; kk < HID; ++kk) {
            p = fmaf(hsm[rr][kk], W2[kk * 4 + o], p);
        }
        out[b * 8 + lane] = (cnt >= 1) ? p : 0.0f;
    }
}

extern "C" void kernel_launch(void* const* d_in, const int* in_sizes, int n_in,
                              void* d_out, int out_size, void* d_ws, size_t ws_size,
                              hipStream_t stream) {
    const float* x    = (const float*)d_in[0];
    const float* Wn   = (const float*)d_in[1];
    const float* bn   = (const float*)d_in[2];
    const float* W1   = (const float*)d_in[3];
    const float* b1   = (const float*)d_in[4];
    const float* W2   = (const float*)d_in[5];
    const float* b2   = (const float*)d_in[6];
    const int*   mask = (const int*)d_in[7];
    float* out = (float*)d_out;

    fused_mlp_topk_kernel<<<BATCH, 64, 0, stream>>>(x, Wn, bn, W1, b1, W2, b2, mask, out);
}